// Round 1
// baseline (650.664 us; speedup 1.0000x reference)
//
#include <hip/hip_runtime.h>

typedef __bf16 bf16x8 __attribute__((ext_vector_type(8)));
typedef float f32x4 __attribute__((ext_vector_type(4)));
typedef unsigned short u16x8 __attribute__((ext_vector_type(8)));

#define L_LEN 16384
#define TILE 128           // l-positions per block (was 256; halved for occupancy)
#define ROWS 142           // TILE + 14 halo rows in LDS
#define XSTR 72            // xT row stride (elements); uniform 8-dword/bank b128 reads
#define WBT_K 960          // 30 ksteps * 32 channels = 15 taps * 64 channels
#define NOC 48             // padded compute output channels (3 N-tiles of 16)

__device__ __forceinline__ unsigned short f2bf(float f) {
  unsigned u = __builtin_bit_cast(unsigned, f);
  u += 0x7fffu + ((u >> 16) & 1u);   // RNE
  return (unsigned short)(u >> 16);
}

// tile0 (oc 0..15: k=1,3,5,7) active ksteps [8,22); tile1 (k=9,11) [4,26); tile2 always
__device__ __forceinline__ bool act0(int s) { return s >= 8 && s < 22; }
__device__ __forceinline__ bool act1(int s) { return s >= 4 && s < 26; }

// compute-oc -> (weight group, local oc, kernel size)
__device__ __forceinline__ void ocmap(int oc, int& gi, int& lo, int& ks) {
  if (oc == 0)       { gi = 0; lo = 0;       ks = 1;  }
  else if (oc <= 5)  { gi = 1; lo = oc - 1;  ks = 3;  }
  else if (oc <= 10) { gi = 2; lo = oc - 6;  ks = 5;  }
  else if (oc <= 15) { gi = 3; lo = oc - 11; ks = 7;  }
  else if (oc <= 20) { gi = 4; lo = oc - 16; ks = 9;  }
  else if (oc <= 25) { gi = 5; lo = oc - 21; ks = 11; }
  else if (oc <= 31) { gi = -1; lo = 0;      ks = 0;  }  // pad
  else if (oc <= 36) { gi = 6; lo = oc - 32; ks = 13; }
  else if (oc <= 41) { gi = 7; lo = oc - 37; ks = 15; }
  else               { gi = -1; lo = 0;      ks = 0;  }  // pad
}

__global__ void prep_kernel(const float* w1, const float* b1, const float* w3, const float* b3,
                            const float* w5, const float* b5, const float* w7, const float* b7,
                            const float* w9, const float* b9, const float* w11, const float* b11,
                            const float* w13, const float* b13, const float* w15, const float* b15,
                            unsigned short* wbt, float* bias) {
  const float* ws[8] = {w1, w3, w5, w7, w9, w11, w13, w15};
  const float* bs[8] = {b1, b3, b5, b7, b9, b11, b13, b15};
  int gid = blockIdx.x * 256 + threadIdx.x;
  if (gid < NOC * WBT_K) {
    int oc = gid / WBT_K;
    int kk = gid - oc * WBT_K;
    int t = kk >> 6;
    int c = kk & 63;
    int gi, lo, ks;
    ocmap(oc, gi, lo, ks);
    float v = 0.f;
    if (gi >= 0) {
      int pad = (ks - 1) >> 1;
      int dk = t - 7 + pad;
      if (dk >= 0 && dk < ks) v = ws[gi][(lo * 64 + c) * ks + dk];
    }
    wbt[gid] = f2bf(v);
  }
  if (gid < NOC) {
    int gi, lo, ks;
    ocmap(gid, gi, lo, ks);
    bias[gid] = (gi >= 0) ? bs[gi][lo] : 0.f;
  }
}

__global__ __launch_bounds__(256, 6)
void Inception1d_62680752718395_kernel(const float* __restrict__ x,
                                       const unsigned short* __restrict__ wbt,
                                       const float* __restrict__ bias,
                                       float* __restrict__ out) {
  __shared__ unsigned short xT[ROWS * XSTR];   // bf16 xT[l_local][c], 20.4 KB (6-8 blocks/CU)

  const int tid = threadIdx.x;
  const int bid = blockIdx.x;
  const int tile = bid & 127;
  const int b = bid >> 7;
  const int l0 = tile * TILE;
  const float* xb = x + (size_t)b * 64 * L_LEN;

  // ---- Stage x[b, :, l0-7 .. l0+134] into xT transposed (bf16), ONE barrier ----
  // task = j*64 + c: a wave spans all 64 channels at one l-quad -> scalar bf16
  // LDS writes hit 32 banks uniformly (2 lanes share a dword: free). 36 quads
  // cover rows -1..142 (edges guarded); 36*64 = 2304 = 9 * 256 tasks exactly.
#pragma unroll
  for (int it = 0; it < 9; ++it) {
    int task = tid + it * 256;
    int j = task >> 6;
    int c = task & 63;
    const float* xrow = xb + (size_t)c * L_LEN;
    int l = l0 - 8 + j * 4;
    float v[4];
    if (l >= 0 && l + 4 <= L_LEN) {
      f32x4 vv = *(const f32x4*)(xrow + l);
#pragma unroll
      for (int e = 0; e < 4; ++e) v[e] = vv[e];
    } else {
#pragma unroll
      for (int e = 0; e < 4; ++e) {
        int le = l + e;
        v[e] = (le >= 0 && le < L_LEN) ? xrow[le] : 0.f;
      }
    }
#pragma unroll
    for (int e = 0; e < 4; ++e) {
      int r = j * 4 + e - 1;                 // xT[r] = x[l0 - 7 + r]
      if (r >= 0 && r < ROWS) xT[r * XSTR + c] = f2bf(v[e]);
    }
  }
  __syncthreads();

  // ---- Fully-unrolled, prefetch-1 software-pipelined MFMA loop (no barriers) ----
  const int lane = tid & 63;
  const int wave = tid >> 6;
  const int n15 = lane & 15;
  const int quad = lane >> 4;

  f32x4 acc0[2], acc1[2], acc2[2];
#pragma unroll
  for (int i = 0; i < 2; ++i) {
    acc0[i] = (f32x4){0.f, 0.f, 0.f, 0.f};
    acc1[i] = (f32x4){0.f, 0.f, 0.f, 0.f};
    acc2[i] = (f32x4){0.f, 0.f, 0.f, 0.f};
  }

  const int abase = (wave * 32 + n15) * XSTR + quad * 8;
  const unsigned short* w0p = wbt + (0 + n15) * WBT_K + quad * 8;
  const unsigned short* w1p = wbt + (16 + n15) * WBT_K + quad * 8;
  const unsigned short* w2p = wbt + (32 + n15) * WBT_K + quad * 8;

  bf16x8 aC[2];
  bf16x8 w0C = {}, w1C = {}, w2C = {};
  {
    // s = 0 loads (only tile2 active)
    const int t = 0, coff = 0;
#pragma unroll
    for (int i = 0; i < 2; ++i)
      aC[i] = __builtin_bit_cast(bf16x8, *(const u16x8*)(&xT[abase + (i * 16 + t) * XSTR + coff]));
    w2C = __builtin_bit_cast(bf16x8, *(const u16x8*)(w2p + 0));
  }

#pragma unroll
  for (int s = 0; s < 30; ++s) {
    bf16x8 aN[2];
    bf16x8 w0N = {}, w1N = {}, w2N = {};
    if (s + 1 < 30) {
      const int sn = s + 1;
      const int t = sn >> 1;
      const int coff = (sn & 1) * 32;
#pragma unroll
      for (int i = 0; i < 2; ++i)
        aN[i] = __builtin_bit_cast(bf16x8, *(const u16x8*)(&xT[abase + (i * 16 + t) * XSTR + coff]));
      if (act0(sn)) w0N = __builtin_bit_cast(bf16x8, *(const u16x8*)(w0p + sn * 32));
      if (act1(sn)) w1N = __builtin_bit_cast(bf16x8, *(const u16x8*)(w1p + sn * 32));
      w2N = __builtin_bit_cast(bf16x8, *(const u16x8*)(w2p + sn * 32));
    } else {
#pragma unroll
      for (int i = 0; i < 2; ++i) aN[i] = aC[i];
    }
    if (act0(s)) {
#pragma unroll
      for (int i = 0; i < 2; ++i)
        acc0[i] = __builtin_amdgcn_mfma_f32_16x16x32_bf16(aC[i], w0C, acc0[i], 0, 0, 0);
    }
    if (act1(s)) {
#pragma unroll
      for (int i = 0; i < 2; ++i)
        acc1[i] = __builtin_amdgcn_mfma_f32_16x16x32_bf16(aC[i], w1C, acc1[i], 0, 0, 0);
    }
#pragma unroll
    for (int i = 0; i < 2; ++i)
      acc2[i] = __builtin_amdgcn_mfma_f32_16x16x32_bf16(aC[i], w2C, acc2[i], 0, 0, 0);
#pragma unroll
    for (int i = 0; i < 2; ++i) aC[i] = aN[i];
    w0C = w0N; w1C = w1N; w2C = w2N;
  }

  // ---- Epilogue: bias + store (compute-oc -> store-oc permutation) ----
  const float bs0 = bias[n15];
  const float bs1 = bias[16 + n15];
  const float bs2 = bias[32 + n15];
  const f32x4 bv0 = {bs0, bs0, bs0, bs0};
  const f32x4 bv1 = {bs1, bs1, bs1, bs1};
  const f32x4 bv2 = {bs2, bs2, bs2, bs2};
  const size_t outb = (size_t)b * 36 * L_LEN;
  const int lbase = l0 + wave * 32 + quad * 4;
#pragma unroll
  for (int i = 0; i < 2; ++i) {
    const int lo_ = lbase + i * 16;
    *(f32x4*)(&out[outb + (size_t)n15 * L_LEN + lo_]) = acc0[i] + bv0;
    if (n15 < 10) {
      *(f32x4*)(&out[outb + (size_t)(16 + n15) * L_LEN + lo_]) = acc1[i] + bv1;
      *(f32x4*)(&out[outb + (size_t)(26 + n15) * L_LEN + lo_]) = acc2[i] + bv2;
    }
  }
}

extern "C" void kernel_launch(void* const* d_in, const int* in_sizes, int n_in,
                              void* d_out, int out_size, void* d_ws, size_t ws_size,
                              hipStream_t stream) {
  const float* x = (const float*)d_in[0];
  const float* w[8];
  const float* bb[8];
  for (int i = 0; i < 8; ++i) {
    w[i] = (const float*)d_in[1 + 2 * i];
    bb[i] = (const float*)d_in[2 + 2 * i];
  }
  unsigned short* wbt = (unsigned short*)d_ws;                    // 48*960 bf16 = 92160 B
  float* bias = (float*)((char*)d_ws + NOC * WBT_K * 2);          // +192 B

  prep_kernel<<<(NOC * WBT_K + 255) / 256, 256, 0, stream>>>(
      w[0], bb[0], w[1], bb[1], w[2], bb[2], w[3], bb[3],
      w[4], bb[4], w[5], bb[5], w[6], bb[6], w[7], bb[7], wbt, bias);

  Inception1d_62680752718395_kernel<<<64 * (L_LEN / TILE), 256, 0, stream>>>(
      x, wbt, bias, (float*)d_out);
}

// Round 3
// 545.745 us; speedup vs baseline: 1.1922x; 1.1922x over previous
//
#include <hip/hip_runtime.h>

typedef __bf16 bf16x8 __attribute__((ext_vector_type(8)));
typedef float f32x4 __attribute__((ext_vector_type(4)));
typedef unsigned short u16x8 __attribute__((ext_vector_type(8)));

#define L_LEN 16384
#define TILE 256           // l-positions per block
#define ROWS 270           // valid r: 0..269; xT row r holds l = l0-7+r
#define WBT_K 960          // 30 ksteps * 32 channels = 15 taps * 64 channels
#define NOC 48             // padded compute output channels (3 N-tiles of 16)

__device__ __forceinline__ unsigned short f2bf(float f) {
  unsigned u = __builtin_bit_cast(unsigned, f);
  u += 0x7fffu + ((u >> 16) & 1u);   // RNE
  return (unsigned short)(u >> 16);
}

// Row-dependent 16B-chunk XOR swizzle for xT (row = 64 bf16 = 8 chunks).
// Spreads (a) coalesced staging writes (r stride 4 per lane group) and
// (b) MFMA b128 reads (r stride 1 across n15) across all 8 chunk groups.
__device__ __forceinline__ int swz(int r) {
  return ((r >> 2) ^ ((r & 3) << 1)) & 7;
}

// tile0 (oc 0..15: k=1,3,5,7) active ksteps [8,22); tile1 (k=9,11) [4,26); tile2 always
__device__ __forceinline__ bool act0(int s) { return s >= 8 && s < 22; }
__device__ __forceinline__ bool act1(int s) { return s >= 4 && s < 26; }

// compute-oc -> (weight group, local oc, kernel size)
__device__ __forceinline__ void ocmap(int oc, int& gi, int& lo, int& ks) {
  if (oc == 0)       { gi = 0; lo = 0;       ks = 1;  }
  else if (oc <= 5)  { gi = 1; lo = oc - 1;  ks = 3;  }
  else if (oc <= 10) { gi = 2; lo = oc - 6;  ks = 5;  }
  else if (oc <= 15) { gi = 3; lo = oc - 11; ks = 7;  }
  else if (oc <= 20) { gi = 4; lo = oc - 16; ks = 9;  }
  else if (oc <= 25) { gi = 5; lo = oc - 21; ks = 11; }
  else if (oc <= 31) { gi = -1; lo = 0;      ks = 0;  }  // pad
  else if (oc <= 36) { gi = 6; lo = oc - 32; ks = 13; }
  else if (oc <= 41) { gi = 7; lo = oc - 37; ks = 15; }
  else               { gi = -1; lo = 0;      ks = 0;  }  // pad
}

__global__ void prep_kernel(const float* w1, const float* b1, const float* w3, const float* b3,
                            const float* w5, const float* b5, const float* w7, const float* b7,
                            const float* w9, const float* b9, const float* w11, const float* b11,
                            const float* w13, const float* b13, const float* w15, const float* b15,
                            unsigned short* wbt, float* bias) {
  const float* ws[8] = {w1, w3, w5, w7, w9, w11, w13, w15};
  const float* bs[8] = {b1, b3, b5, b7, b9, b11, b13, b15};
  int gid = blockIdx.x * 256 + threadIdx.x;
  if (gid < NOC * WBT_K) {
    int oc = gid / WBT_K;
    int kk = gid - oc * WBT_K;
    int t = kk >> 6;
    int c = kk & 63;
    int gi, lo, ks;
    ocmap(oc, gi, lo, ks);
    float v = 0.f;
    if (gi >= 0) {
      int pad = (ks - 1) >> 1;
      int dk = t - 7 + pad;
      if (dk >= 0 && dk < ks) v = ws[gi][(lo * 64 + c) * ks + dk];
    }
    wbt[gid] = f2bf(v);
  }
  if (gid < NOC) {
    int gi, lo, ks;
    ocmap(gid, gi, lo, ks);
    bias[gid] = (gi >= 0) ? bs[gi][lo] : 0.f;
  }
}

__global__ __launch_bounds__(256, 4)
void Inception1d_62680752718395_kernel(const float* __restrict__ x,
                                       const unsigned short* __restrict__ wbt,
                                       const float* __restrict__ bias,
                                       float* __restrict__ out) {
  // bf16 xT[r][c], 128 B rows, XOR-chunk-swizzled; 34.6 KB -> 4 blocks/CU
  __shared__ __align__(16) unsigned short xT[ROWS * 64];

  const int tid = threadIdx.x;
  const int bid = blockIdx.x;
  const int tile = bid & 63;
  const int b = bid >> 6;
  const int l0 = tile * TILE;
  const float* xb = x + (size_t)b * 64 * L_LEN;

  const int lane = tid & 63;
  const int wave = tid >> 6;

  // ---- Stage x[b, :, l0-8 .. l0+263] into xT (bf16, swizzled), ONE barrier ----
  // COALESCED: each wave-instr covers 4 channels x 16 consecutive l-quads
  // -> 16 unique 64B lines per instruction, each fetched byte used exactly once
  // (the old 64-channel gather was 64 lines/instr, each looked up 4x).
#pragma unroll
  for (int it = 0; it < 16; ++it) {
    const int u = it * 4 + wave;                 // 64 units: (c-block, j-window)
    const int c = (u & 15) * 4 + (lane >> 4);    // 4-channel block
    const int j = ((u >> 4) << 4) + (lane & 15); // 16-quad window, j 0..63
    const float* xrow = xb + (size_t)c * L_LEN;
    const int l = l0 - 8 + j * 4;
    float v[4];
    if (l >= 0 && l + 4 <= L_LEN) {
      f32x4 vv = *(const f32x4*)(xrow + l);
#pragma unroll
      for (int e = 0; e < 4; ++e) v[e] = vv[e];
    } else {
#pragma unroll
      for (int e = 0; e < 4; ++e) {
        int le = l + e;
        v[e] = (le >= 0 && le < L_LEN) ? xrow[le] : 0.f;
      }
    }
#pragma unroll
    for (int e = 0; e < 4; ++e) {
      int r = j * 4 + e - 1;                     // xT row r = x[l0 - 7 + r]
      if (r >= 0 && r < ROWS)
        xT[r * 64 + ((((c >> 3) ^ swz(r)) << 3) | (c & 7))] = f2bf(v[e]);
    }
  }
  // tail: j 64..67 (l0+248 .. l0+263), 64 channels x 4 quads
  {
    const int c = tid >> 2;
    const int j = 64 + (tid & 3);
    const float* xrow = xb + (size_t)c * L_LEN;
    const int l = l0 - 8 + j * 4;
    float v[4];
    if (l >= 0 && l + 4 <= L_LEN) {
      f32x4 vv = *(const f32x4*)(xrow + l);
#pragma unroll
      for (int e = 0; e < 4; ++e) v[e] = vv[e];
    } else {
#pragma unroll
      for (int e = 0; e < 4; ++e) {
        int le = l + e;
        v[e] = (le >= 0 && le < L_LEN) ? xrow[le] : 0.f;
      }
    }
#pragma unroll
    for (int e = 0; e < 4; ++e) {
      int r = j * 4 + e - 1;
      if (r >= 0 && r < ROWS)
        xT[r * 64 + ((((c >> 3) ^ swz(r)) << 3) | (c & 7))] = f2bf(v[e]);
    }
  }
  __syncthreads();

  // ---- Fully-unrolled, prefetch-1 software-pipelined MFMA loop (no barriers) ----
  const int n15 = lane & 15;
  const int quad = lane >> 4;

  f32x4 acc0[4], acc1[4], acc2[4];
#pragma unroll
  for (int i = 0; i < 4; ++i) {
    acc0[i] = (f32x4){0.f, 0.f, 0.f, 0.f};
    acc1[i] = (f32x4){0.f, 0.f, 0.f, 0.f};
    acc2[i] = (f32x4){0.f, 0.f, 0.f, 0.f};
  }

  const int rb = wave * 64 + n15;                 // A-row base (l index in xT)
  const unsigned short* w0p = wbt + (0 + n15) * WBT_K + quad * 8;
  const unsigned short* w1p = wbt + (16 + n15) * WBT_K + quad * 8;
  const unsigned short* w2p = wbt + (32 + n15) * WBT_K + quad * 8;

  bf16x8 aC[4];
  bf16x8 w0C = {}, w1C = {}, w2C = {};
  {
    // s = 0 loads (only tile2 active): t=0, chunk M=quad
#pragma unroll
    for (int i = 0; i < 4; ++i) {
      const int r = rb + i * 16;
      aC[i] = __builtin_bit_cast(bf16x8,
          *(const u16x8*)(&xT[r * 64 + (((quad ^ swz(r)) & 7) << 3)]));
    }
    w2C = __builtin_bit_cast(bf16x8, *(const u16x8*)(w2p + 0));
  }

#pragma unroll
  for (int s = 0; s < 30; ++s) {
    bf16x8 aN[4];
    bf16x8 w0N = {}, w1N = {}, w2N = {};
    if (s + 1 < 30) {
      const int sn = s + 1;
      const int t = sn >> 1;
      const int M = quad + ((sn & 1) << 2);       // 16B chunk index (pre-swizzle)
#pragma unroll
      for (int i = 0; i < 4; ++i) {
        const int r = rb + i * 16 + t;
        aN[i] = __builtin_bit_cast(bf16x8,
            *(const u16x8*)(&xT[r * 64 + (((M ^ swz(r)) & 7) << 3)]));
      }
      if (act0(sn)) w0N = __builtin_bit_cast(bf16x8, *(const u16x8*)(w0p + sn * 32));
      if (act1(sn)) w1N = __builtin_bit_cast(bf16x8, *(const u16x8*)(w1p + sn * 32));
      w2N = __builtin_bit_cast(bf16x8, *(const u16x8*)(w2p + sn * 32));
    } else {
#pragma unroll
      for (int i = 0; i < 4; ++i) aN[i] = aC[i];
    }
    if (act0(s)) {
#pragma unroll
      for (int i = 0; i < 4; ++i)
        acc0[i] = __builtin_amdgcn_mfma_f32_16x16x32_bf16(aC[i], w0C, acc0[i], 0, 0, 0);
    }
    if (act1(s)) {
#pragma unroll
      for (int i = 0; i < 4; ++i)
        acc1[i] = __builtin_amdgcn_mfma_f32_16x16x32_bf16(aC[i], w1C, acc1[i], 0, 0, 0);
    }
#pragma unroll
    for (int i = 0; i < 4; ++i)
      acc2[i] = __builtin_amdgcn_mfma_f32_16x16x32_bf16(aC[i], w2C, acc2[i], 0, 0, 0);
#pragma unroll
    for (int i = 0; i < 4; ++i) aC[i] = aN[i];
    w0C = w0N; w1C = w1N; w2C = w2N;
  }

  // ---- Epilogue: bias + store (compute-oc -> store-oc permutation) ----
  const float bs0 = bias[n15];
  const float bs1 = bias[16 + n15];
  const float bs2 = bias[32 + n15];
  const f32x4 bv0 = {bs0, bs0, bs0, bs0};
  const f32x4 bv1 = {bs1, bs1, bs1, bs1};
  const f32x4 bv2 = {bs2, bs2, bs2, bs2};
  const size_t outb = (size_t)b * 36 * L_LEN;
  const int lbase = l0 + wave * 64 + quad * 4;
#pragma unroll
  for (int i = 0; i < 4; ++i) {
    const int lo_ = lbase + i * 16;
    *(f32x4*)(&out[outb + (size_t)n15 * L_LEN + lo_]) = acc0[i] + bv0;
    if (n15 < 10) {
      *(f32x4*)(&out[outb + (size_t)(16 + n15) * L_LEN + lo_]) = acc1[i] + bv1;
      *(f32x4*)(&out[outb + (size_t)(26 + n15) * L_LEN + lo_]) = acc2[i] + bv2;
    }
  }
}

extern "C" void kernel_launch(void* const* d_in, const int* in_sizes, int n_in,
                              void* d_out, int out_size, void* d_ws, size_t ws_size,
                              hipStream_t stream) {
  const float* x = (const float*)d_in[0];
  const float* w[8];
  const float* bb[8];
  for (int i = 0; i < 8; ++i) {
    w[i] = (const float*)d_in[1 + 2 * i];
    bb[i] = (const float*)d_in[2 + 2 * i];
  }
  unsigned short* wbt = (unsigned short*)d_ws;                    // 48*960 bf16 = 92160 B
  float* bias = (float*)((char*)d_ws + NOC * WBT_K * 2);          // +192 B

  prep_kernel<<<(NOC * WBT_K + 255) / 256, 256, 0, stream>>>(
      w[0], bb[0], w[1], bb[1], w[2], bb[2], w[3], bb[3],
      w[4], bb[4], w[5], bb[5], w[6], bb[6], w[7], bb[7], wbt, bias);

  Inception1d_62680752718395_kernel<<<64 * (L_LEN / TILE), 256, 0, stream>>>(
      x, wbt, bias, (float*)d_out);
}